// Round 1
// baseline (244.792 us; speedup 1.0000x reference)
//
#include <hip/hip_runtime.h>

#define BB 8
#define CC 64
#define HH 256
#define WW 256
#define H1 128
#define W1 128
#define H2 64
#define W2 64
#define KK 5

// ---------------------------------------------------------------------------
// Kernel 1: fused avgpool(2x2) + 3x depthwise conv 5x5 (block1) on 128x128
// One block = one 32x32 output tile of one (b,c) plane.
// LDS ping-pong: sA 44x44 (avgpool+halo6) -> sB 40x40 -> sA 36x36 -> out 32x32
// ---------------------------------------------------------------------------
__global__ __launch_bounds__(256) void k_block1(
    const float* __restrict__ x, const float* __restrict__ w1,
    const float* __restrict__ b1, float* __restrict__ t1)
{
    const int plane = blockIdx.z;          // b*64 + c
    const int c = plane & 63;
    const int tx = blockIdx.x, ty = blockIdx.y;
    const int tid = threadIdx.x;

    __shared__ float sA[44 * 44];
    __shared__ float sB[40 * 40];
    __shared__ float sw[3 * 25];
    __shared__ float sb[3];

    if (tid < 75) sw[tid] = w1[(tid / 25) * CC * 25 + c * 25 + (tid % 25)];
    if (tid < 3)  sb[tid] = b1[tid * CC + c];

    const float* xp = x + (size_t)plane * HH * WW;
    const int row0 = ty * 32 - 6, col0 = tx * 32 - 6;

    // avgpool load with zero halo (outside the 128x128 pooled image)
    for (int i = tid; i < 44 * 44; i += 256) {
        int r = i / 44, cc2 = i % 44;
        int gr = row0 + r, gc = col0 + cc2;
        float v = 0.f;
        if ((unsigned)gr < H1 && (unsigned)gc < W1) {
            const float* p = xp + (size_t)(2 * gr) * WW + 2 * gc;
            v = 0.25f * (p[0] + p[1] + p[WW] + p[WW + 1]);
        }
        sA[i] = v;
    }
    __syncthreads();

    // conv1: sA(44^2) -> sB(40^2); zero outside-image halo positions
    for (int i = tid; i < 40 * 40; i += 256) {
        int r = i / 40, cc2 = i % 40;
        int gr = row0 + 2 + r, gc = col0 + 2 + cc2;
        float v = 0.f;
        if ((unsigned)gr < H1 && (unsigned)gc < W1) {
            v = sb[0];
#pragma unroll
            for (int ky = 0; ky < KK; ky++)
#pragma unroll
                for (int kx = 0; kx < KK; kx++)
                    v += sA[(r + ky) * 44 + cc2 + kx] * sw[ky * 5 + kx];
        }
        sB[i] = v;
    }
    __syncthreads();

    // conv2: sB(40^2) -> sA(36^2)
    for (int i = tid; i < 36 * 36; i += 256) {
        int r = i / 36, cc2 = i % 36;
        int gr = row0 + 4 + r, gc = col0 + 4 + cc2;
        float v = 0.f;
        if ((unsigned)gr < H1 && (unsigned)gc < W1) {
            v = sb[1];
#pragma unroll
            for (int ky = 0; ky < KK; ky++)
#pragma unroll
                for (int kx = 0; kx < KK; kx++)
                    v += sB[(r + ky) * 40 + cc2 + kx] * sw[25 + ky * 5 + kx];
        }
        sA[i] = v;
    }
    __syncthreads();

    // conv3: sA(36^2) -> global 32x32 (always interior)
    float* tp = t1 + (size_t)plane * H1 * W1;
    for (int i = tid; i < 32 * 32; i += 256) {
        int r = i / 32, cc2 = i % 32;
        float v = sb[2];
#pragma unroll
        for (int ky = 0; ky < KK; ky++)
#pragma unroll
            for (int kx = 0; kx < KK; kx++)
                v += sA[(r + ky) * 36 + cc2 + kx] * sw[50 + ky * 5 + kx];
        tp[(size_t)(ty * 32 + r) * W1 + tx * 32 + cc2] = v;
    }
}

// ---------------------------------------------------------------------------
// Kernel 2: per-(b,c)-plane fused maxpool(2x2) + 3x dwconv 5x5 + global mean
// One block per plane (512 blocks). Full 64x64 plane ping-pongs in LDS.
// ---------------------------------------------------------------------------
__global__ __launch_bounds__(256) void k_block2(
    const float* __restrict__ t1, const float* __restrict__ w2,
    const float* __restrict__ b2, float* __restrict__ g)
{
    const int plane = blockIdx.x;
    const int c = plane & 63;
    const int tid = threadIdx.x;

    __shared__ float sA[64 * 64];
    __shared__ float sB[64 * 64];
    __shared__ float sw[3 * 25];
    __shared__ float sb[3];
    __shared__ float red[4];

    if (tid < 75) sw[tid] = w2[(tid / 25) * CC * 25 + c * 25 + (tid % 25)];
    if (tid < 3)  sb[tid] = b2[tid * CC + c];

    const float* tp = t1 + (size_t)plane * H1 * W1;
    for (int i = tid; i < 64 * 64; i += 256) {
        int r = i >> 6, cc2 = i & 63;
        const float* p = tp + (size_t)(2 * r) * W1 + 2 * cc2;
        sA[i] = fmaxf(fmaxf(p[0], p[1]), fmaxf(p[W1], p[W1 + 1]));
    }
    __syncthreads();

    // 3 convs with zero padding, ping-pong sA <-> sB
#pragma unroll
    for (int cv = 0; cv < 3; cv++) {
        const float* src = (cv & 1) ? sB : sA;
        float* dst = (cv & 1) ? sA : sB;
        float bv = sb[cv];
        const float* wv = &sw[cv * 25];
        for (int i = tid; i < 64 * 64; i += 256) {
            int r = i >> 6, cc2 = i & 63;
            float v = bv;
#pragma unroll
            for (int ky = 0; ky < KK; ky++) {
                int ir = r + ky - 2;
                if ((unsigned)ir < 64) {
#pragma unroll
                    for (int kx = 0; kx < KK; kx++) {
                        int ic = cc2 + kx - 2;
                        if ((unsigned)ic < 64) v += src[ir * 64 + ic] * wv[ky * 5 + kx];
                    }
                }
            }
            dst[i] = v;
        }
        __syncthreads();
    }

    // mean of sB (after 3rd conv, result is in sB since cv=2 wrote dst=sB)
    float s = 0.f;
    for (int i = tid; i < 64 * 64; i += 256) s += sB[i];
#pragma unroll
    for (int off = 32; off > 0; off >>= 1) s += __shfl_down(s, off);
    if ((tid & 63) == 0) red[tid >> 6] = s;
    __syncthreads();
    if (tid == 0) g[plane] = (red[0] + red[1] + red[2] + red[3]) * (1.f / 4096.f);
}

// ---------------------------------------------------------------------------
// Kernel 3: kern[b, o] = dot(g[b,:], wk[o,:]) + bk[o], o in [0,1600)
// kern flat layout [b*1600 + ch*25 + kk] == [plane*25 + kk]
// ---------------------------------------------------------------------------
__global__ __launch_bounds__(256) void k_kern(
    const float* __restrict__ g, const float* __restrict__ wk,
    const float* __restrict__ bk, float* __restrict__ kern)
{
    const int b = blockIdx.x;  // 8
    const int tid = threadIdx.x;
    __shared__ float sg[64];
    if (tid < 64) sg[tid] = g[b * 64 + tid];
    __syncthreads();
    for (int o = tid; o < 1600; o += 256) {
        float v = bk[o];
        const float* wp = wk + (size_t)o * 64;
#pragma unroll 8
        for (int cc2 = 0; cc2 < 64; cc2++) v += sg[cc2] * wp[cc2];
        kern[b * 1600 + o] = v;
    }
}

// ---------------------------------------------------------------------------
// Kernel 4: dynamic depthwise conv 5x5 on x (256x256), per-plane kernel.
// Tile 64x16 outputs, LDS halo tile 68x20, 4 outputs/thread, float4 stores.
// ---------------------------------------------------------------------------
__global__ __launch_bounds__(256) void k_dyn(
    const float* __restrict__ x, const float* __restrict__ kern,
    const float* __restrict__ bias, float* __restrict__ out)
{
    const int plane = blockIdx.z;          // b*64 + c
    const int c = plane & 63;
    const int tx = blockIdx.x;             // 0..3   (cols of 64)
    const int ty = blockIdx.y;             // 0..15  (rows of 16)
    const int tid = threadIdx.x;

    __shared__ float sx[20 * 68];
    __shared__ float sk[25];
    if (tid < 25) sk[tid] = kern[(size_t)plane * 25 + tid];

    const float* xp = x + (size_t)plane * HH * WW;
    const int row0 = ty * 16 - 2, col0 = tx * 64 - 2;
    for (int i = tid; i < 20 * 68; i += 256) {
        int r = i / 68, cc2 = i % 68;
        int gr = row0 + r, gc = col0 + cc2;
        float v = 0.f;
        if ((unsigned)gr < HH && (unsigned)gc < WW) v = xp[(size_t)gr * WW + gc];
        sx[i] = v;
    }
    __syncthreads();

    const float bv = bias[c];
    const int r = tid >> 4;                // 0..15
    const int c4 = (tid & 15) * 4;         // 0..60
    float a0 = bv, a1 = bv, a2 = bv, a3 = bv;
#pragma unroll
    for (int ky = 0; ky < KK; ky++) {
#pragma unroll
        for (int kx = 0; kx < KK; kx++) {
            float w = sk[ky * 5 + kx];
            const float* p = &sx[(r + ky) * 68 + c4 + kx];
            a0 += p[0] * w; a1 += p[1] * w; a2 += p[2] * w; a3 += p[3] * w;
        }
    }
    float4 o4 = make_float4(a0, a1, a2, a3);
    *(float4*)&out[(size_t)plane * HH * WW + (size_t)(ty * 16 + r) * WW + tx * 64 + c4] = o4;
}

// ---------------------------------------------------------------------------
extern "C" void kernel_launch(void* const* d_in, const int* in_sizes, int n_in,
                              void* d_out, int out_size, void* d_ws, size_t ws_size,
                              hipStream_t stream)
{
    const float* x    = (const float*)d_in[0];
    const float* w1   = (const float*)d_in[1];
    const float* b1   = (const float*)d_in[2];
    const float* w2   = (const float*)d_in[3];
    const float* b2   = (const float*)d_in[4];
    const float* wk   = (const float*)d_in[5];
    const float* bk   = (const float*)d_in[6];
    const float* bias = (const float*)d_in[7];
    float* out = (float*)d_out;

    float* ws   = (float*)d_ws;
    float* t1   = ws;                       // 512 * 128 * 128 = 8388608 floats
    float* g    = ws + 8388608;             // 512 floats
    float* kern = g + 512;                  // 12800 floats

    k_block1<<<dim3(4, 4, 512), 256, 0, stream>>>(x, w1, b1, t1);
    k_block2<<<dim3(512), 256, 0, stream>>>(t1, w2, b2, g);
    k_kern<<<dim3(8), 256, 0, stream>>>(g, wk, bk, kern);
    k_dyn<<<dim3(4, 16, 512), 256, 0, stream>>>(x, kern, bias, out);
}

// Round 2
// 195.741 us; speedup vs baseline: 1.2506x; 1.2506x over previous
//
#include <hip/hip_runtime.h>

#define BB 8
#define CC 64
#define HH 256
#define WW 256
#define H1 128
#define W1 128
#define KK 5

// 4-wide strip of a 5-tap conv row: 2 aligned float4 LDS reads, 20 FMAs.
__device__ __forceinline__ void conv5_row(const float* __restrict__ s,
                                          const float* __restrict__ w,
                                          float& a0, float& a1, float& a2, float& a3)
{
    float4 L = *(const float4*)s;
    float4 R = *(const float4*)(s + 4);
    a0 += w[0]*L.x + w[1]*L.y + w[2]*L.z + w[3]*L.w + w[4]*R.x;
    a1 += w[0]*L.y + w[1]*L.z + w[2]*L.w + w[3]*R.x + w[4]*R.y;
    a2 += w[0]*L.z + w[1]*L.w + w[2]*R.x + w[3]*R.y + w[4]*R.z;
    a3 += w[0]*L.w + w[1]*R.x + w[2]*R.y + w[3]*R.z + w[4]*R.w;
}

// ---------------------------------------------------------------------------
// Kernel 1: fused avgpool(2x2) + 3x depthwise conv 5x5 (block1) on 128x128
// One block = one 64x64 output tile. LDS ping-pong 76^2 -> 72^2 -> 68^2 -> out.
// ---------------------------------------------------------------------------
__global__ __launch_bounds__(256) void k_block1(
    const float* __restrict__ x, const float* __restrict__ w1,
    const float* __restrict__ b1, float* __restrict__ t1)
{
    const int plane = blockIdx.z;          // b*64 + c
    const int c = plane & 63;
    const int tx = blockIdx.x, ty = blockIdx.y;   // 2x2 tiles
    const int tid = threadIdx.x;

    __shared__ __align__(16) float sA[76 * 76];
    __shared__ __align__(16) float sB[72 * 72];
    __shared__ float sw[80];
    __shared__ float sb[4];

    if (tid < 75) sw[tid] = w1[(tid / 25) * CC * 25 + c * 25 + (tid % 25)];
    if (tid < 3)  sb[tid] = b1[tid * CC + c];

    const float* xp = x + (size_t)plane * HH * WW;
    const int row0 = ty * 64 - 6, col0 = tx * 64 - 6;

    // avgpool load with zero halo
    for (int i = tid; i < 76 * 76; i += 256) {
        int r = i / 76, cc2 = i % 76;
        int gr = row0 + r, gc = col0 + cc2;
        float v = 0.f;
        if ((unsigned)gr < H1 && (unsigned)gc < W1) {
            const float* p = xp + (size_t)(2 * gr) * WW + 2 * gc;
            v = 0.25f * (p[0] + p[1] + p[WW] + p[WW + 1]);
        }
        sA[i] = v;
    }
    __syncthreads();

    // conv1: sA(76^2,stride76) -> sB(72^2,stride72)
    {
        float wr[25];
#pragma unroll
        for (int k = 0; k < 25; k++) wr[k] = sw[k];
        const float bv = sb[0];
        for (int i = tid; i < 72 * 18; i += 256) {
            int r = i / 18, s4 = (i % 18) * 4;
            float a0 = bv, a1 = bv, a2 = bv, a3 = bv;
#pragma unroll
            for (int ky = 0; ky < KK; ky++)
                conv5_row(&sA[(r + ky) * 76 + s4], &wr[ky * 5], a0, a1, a2, a3);
            int gr = row0 + 2 + r, gc = col0 + 2 + s4;
            bool rok = (unsigned)gr < H1;
            a0 = (rok && (unsigned)(gc + 0) < W1) ? a0 : 0.f;
            a1 = (rok && (unsigned)(gc + 1) < W1) ? a1 : 0.f;
            a2 = (rok && (unsigned)(gc + 2) < W1) ? a2 : 0.f;
            a3 = (rok && (unsigned)(gc + 3) < W1) ? a3 : 0.f;
            *(float4*)&sB[r * 72 + s4] = make_float4(a0, a1, a2, a3);
        }
    }
    __syncthreads();

    // conv2: sB(72^2) -> sA(68^2,stride68)  (sA pool data dead now)
    {
        float wr[25];
#pragma unroll
        for (int k = 0; k < 25; k++) wr[k] = sw[25 + k];
        const float bv = sb[1];
        for (int i = tid; i < 68 * 17; i += 256) {
            int r = i / 17, s4 = (i % 17) * 4;
            float a0 = bv, a1 = bv, a2 = bv, a3 = bv;
#pragma unroll
            for (int ky = 0; ky < KK; ky++)
                conv5_row(&sB[(r + ky) * 72 + s4], &wr[ky * 5], a0, a1, a2, a3);
            int gr = row0 + 4 + r, gc = col0 + 4 + s4;
            bool rok = (unsigned)gr < H1;
            a0 = (rok && (unsigned)(gc + 0) < W1) ? a0 : 0.f;
            a1 = (rok && (unsigned)(gc + 1) < W1) ? a1 : 0.f;
            a2 = (rok && (unsigned)(gc + 2) < W1) ? a2 : 0.f;
            a3 = (rok && (unsigned)(gc + 3) < W1) ? a3 : 0.f;
            *(float4*)&sA[r * 68 + s4] = make_float4(a0, a1, a2, a3);
        }
    }
    __syncthreads();

    // conv3: sA(68^2) -> global 64x64 (always interior)
    {
        float wr[25];
#pragma unroll
        for (int k = 0; k < 25; k++) wr[k] = sw[50 + k];
        const float bv = sb[2];
        float* tp = t1 + (size_t)plane * H1 * W1;
        for (int i = tid; i < 64 * 16; i += 256) {
            int r = i >> 4, s4 = (i & 15) * 4;
            float a0 = bv, a1 = bv, a2 = bv, a3 = bv;
#pragma unroll
            for (int ky = 0; ky < KK; ky++)
                conv5_row(&sA[(r + ky) * 68 + s4], &wr[ky * 5], a0, a1, a2, a3);
            *(float4*)&tp[(size_t)(ty * 64 + r) * W1 + tx * 64 + s4] =
                make_float4(a0, a1, a2, a3);
        }
    }
}

// ---------------------------------------------------------------------------
// Kernel 2: per-plane maxpool(2x2) + 3x dwconv 5x5 + mean. Zero-padded 68x68
// LDS buffers, no boundary branches in conv loops.
// ---------------------------------------------------------------------------
__global__ __launch_bounds__(256) void k_block2(
    const float* __restrict__ t1, const float* __restrict__ w2,
    const float* __restrict__ b2, float* __restrict__ g)
{
    const int plane = blockIdx.x;
    const int c = plane & 63;
    const int tid = threadIdx.x;

    __shared__ __align__(16) float sA[68 * 68];
    __shared__ __align__(16) float sB[68 * 68];
    __shared__ float sw[80];
    __shared__ float sb[4];
    __shared__ float red[4];

    if (tid < 75) sw[tid] = w2[(tid / 25) * CC * 25 + c * 25 + (tid % 25)];
    if (tid < 3)  sb[tid] = b2[tid * CC + c];

    const float* tp = t1 + (size_t)plane * H1 * W1;
    for (int i = tid; i < 68 * 68; i += 256) {
        int r = i / 68, cc2 = i % 68;
        float v = 0.f;
        if (r >= 2 && r < 66 && cc2 >= 2 && cc2 < 66) {
            const float* p = tp + (size_t)(2 * (r - 2)) * W1 + 2 * (cc2 - 2);
            v = fmaxf(fmaxf(p[0], p[1]), fmaxf(p[W1], p[W1 + 1]));
        }
        sA[i] = v;
        sB[i] = 0.f;
    }
    __syncthreads();

    // 3 convs, ping-pong; src/dst interiors, borders stay zero
#pragma unroll
    for (int cv = 0; cv < 3; cv++) {
        const float* src = (cv & 1) ? sB : sA;
        float* dst = (cv & 1) ? sA : sB;
        float wr[25];
#pragma unroll
        for (int k = 0; k < 25; k++) wr[k] = sw[cv * 25 + k];
        const float bv = sb[cv];
#pragma unroll
        for (int it = 0; it < 4; it++) {
            int i = it * 256 + tid;            // 64 rows x 16 strips
            int r = i >> 4, s4 = (i & 15) * 4;
            float a0 = bv, a1 = bv, a2 = bv, a3 = bv;
#pragma unroll
            for (int ky = 0; ky < KK; ky++)
                conv5_row(&src[(r + ky) * 68 + s4], &wr[ky * 5], a0, a1, a2, a3);
            float* d = &dst[(r + 2) * 68 + 2 + s4];
            d[0] = a0; d[1] = a1; d[2] = a2; d[3] = a3;
        }
        __syncthreads();
    }

    // mean of sB interior (cv=2 wrote sB)
    float s = 0.f;
    for (int i = tid; i < 64 * 64; i += 256) {
        int r = i >> 6, cc2 = i & 63;
        s += sB[(r + 2) * 68 + 2 + cc2];
    }
#pragma unroll
    for (int off = 32; off > 0; off >>= 1) s += __shfl_down(s, off);
    if ((tid & 63) == 0) red[tid >> 6] = s;
    __syncthreads();
    if (tid == 0) g[plane] = (red[0] + red[1] + red[2] + red[3]) * (1.f / 4096.f);
}

// ---------------------------------------------------------------------------
// Kernel 3: kern[o_global] = dot(g[b,:], wk[o,:]) + bk[o];  50*256 = 12800
// ---------------------------------------------------------------------------
__global__ __launch_bounds__(256) void k_kern(
    const float* __restrict__ g, const float* __restrict__ wk,
    const float* __restrict__ bk, float* __restrict__ kern)
{
    const int o = blockIdx.x * 256 + threadIdx.x;     // 0..12799
    const int b = o / 1600, oo = o - b * 1600;
    float v = bk[oo];
    const float* wp = wk + (size_t)oo * 64;
    const float* gp = g + b * 64;
#pragma unroll 16
    for (int k = 0; k < 64; k++) v += gp[k] * wp[k];
    kern[o] = v;
}

// ---------------------------------------------------------------------------
// Kernel 4: dynamic depthwise conv 5x5, 64x64 tile, 4x4 outputs/thread,
// one ds_read_b128 per output (row-reuse register blocking).
// ---------------------------------------------------------------------------
__global__ __launch_bounds__(256) void k_dyn(
    const float* __restrict__ x, const float* __restrict__ kern,
    const float* __restrict__ bias, float* __restrict__ out)
{
    const int plane = blockIdx.z;          // b*64 + c
    const int c = plane & 63;
    const int tx = blockIdx.x, ty = blockIdx.y;   // 4x4 tiles of 64x64
    const int tid = threadIdx.x;

    __shared__ __align__(16) float sx[68 * 68];
    __shared__ float sk[32];
    if (tid < 25) sk[tid] = kern[(size_t)plane * 25 + tid];

    const float* xp = x + (size_t)plane * HH * WW;
    const int row0 = ty * 64 - 2, col0 = tx * 64 - 2;
    for (int i = tid; i < 68 * 68; i += 256) {
        int r = i / 68, cc2 = i % 68;
        int gr = row0 + r, gc = col0 + cc2;
        float v = 0.f;
        if ((unsigned)gr < HH && (unsigned)gc < WW) v = xp[(size_t)gr * WW + gc];
        sx[i] = v;
    }
    __syncthreads();

    float w[25];
#pragma unroll
    for (int k = 0; k < 25; k++) w[k] = sk[k];
    const float bv = bias[c];

    const int tr = (tid >> 4) * 4;      // output row base 0..60
    const int tc = (tid & 15) * 4;      // output col base 0..60
    float acc[4][4];
#pragma unroll
    for (int i = 0; i < 4; i++)
#pragma unroll
        for (int j = 0; j < 4; j++) acc[i][j] = bv;

#pragma unroll
    for (int ir = 0; ir < 8; ir++) {
        const float* s = &sx[(tr + ir) * 68 + tc];
        float4 L = *(const float4*)s;
        float4 R = *(const float4*)(s + 4);
        float e[8] = {L.x, L.y, L.z, L.w, R.x, R.y, R.z, R.w};
#pragma unroll
        for (int i = 0; i < 4; i++) {
            const int ky = ir - i;
            if (ky >= 0 && ky < 5) {
#pragma unroll
                for (int kx = 0; kx < 5; kx++) {
                    const float wv = w[ky * 5 + kx];
#pragma unroll
                    for (int j = 0; j < 4; j++) acc[i][j] += e[j + kx] * wv;
                }
            }
        }
    }

    float* op = out + (size_t)plane * HH * WW + (size_t)(ty * 64 + tr) * WW + tx * 64 + tc;
#pragma unroll
    for (int i = 0; i < 4; i++)
        *(float4*)(op + (size_t)i * WW) = make_float4(acc[i][0], acc[i][1], acc[i][2], acc[i][3]);
}

// ---------------------------------------------------------------------------
extern "C" void kernel_launch(void* const* d_in, const int* in_sizes, int n_in,
                              void* d_out, int out_size, void* d_ws, size_t ws_size,
                              hipStream_t stream)
{
    const float* x    = (const float*)d_in[0];
    const float* w1   = (const float*)d_in[1];
    const float* b1   = (const float*)d_in[2];
    const float* w2   = (const float*)d_in[3];
    const float* b2   = (const float*)d_in[4];
    const float* wk   = (const float*)d_in[5];
    const float* bk   = (const float*)d_in[6];
    const float* bias = (const float*)d_in[7];
    float* out = (float*)d_out;

    float* ws   = (float*)d_ws;
    float* t1   = ws;                       // 512*128*128 floats
    float* g    = ws + 8388608;             // 512 floats
    float* kern = g + 512;                  // 12800 floats

    k_block1<<<dim3(2, 2, 512), 256, 0, stream>>>(x, w1, b1, t1);
    k_block2<<<dim3(512), 256, 0, stream>>>(t1, w2, b2, g);
    k_kern<<<dim3(50), 256, 0, stream>>>(g, wk, bk, kern);
    k_dyn<<<dim3(4, 4, 512), 256, 0, stream>>>(x, kern, bias, out);
}

// Round 4
// 161.693 us; speedup vs baseline: 1.5139x; 1.2106x over previous
//
#include <hip/hip_runtime.h>

#define BB 8
#define CC 64
#define HH 256
#define WW 256
#define H1 128
#define W1 128
#define KK 5

// 2x4 output register block of a 5x5 conv: 6 rows x 2 ds_read_b128, 200 FMA.
template<int SS>
__device__ __forceinline__ void conv2x4(const float* __restrict__ src,
                                        const float* __restrict__ wr,
                                        float bv, float a[2][4])
{
#pragma unroll
    for (int i = 0; i < 2; i++)
#pragma unroll
        for (int j = 0; j < 4; j++) a[i][j] = bv;
#pragma unroll
    for (int ir = 0; ir < 6; ir++) {
        const float* s = src + ir * SS;
        float4 L = *(const float4*)s;
        float4 R = *(const float4*)(s + 4);
        float e[8] = {L.x, L.y, L.z, L.w, R.x, R.y, R.z, R.w};
        if (ir <= 4) {
#pragma unroll
            for (int kx = 0; kx < 5; kx++) {
                float w0 = wr[ir * 5 + kx];
#pragma unroll
                for (int j = 0; j < 4; j++) a[0][j] += e[j + kx] * w0;
            }
        }
        if (ir >= 1) {
#pragma unroll
            for (int kx = 0; kx < 5; kx++) {
                float w1 = wr[(ir - 1) * 5 + kx];
#pragma unroll
                for (int j = 0; j < 4; j++) a[1][j] += e[j + kx] * w1;
            }
        }
    }
}

// ---------------------------------------------------------------------------
// Kernel 1: fused avgpool(2x2) + 3x depthwise conv 5x5 (block1) on 128x128
// 64x64 tile / block, 512 threads. Ping-pong sA(76) -> sB(72) -> sA(68) -> out
// ---------------------------------------------------------------------------
__global__ __launch_bounds__(512, 4) void k_block1(
    const float* __restrict__ x, const float* __restrict__ w1,
    const float* __restrict__ b1, float* __restrict__ t1)
{
    const int plane = blockIdx.z;          // b*64 + c
    const int c = plane & 63;
    const int tx = blockIdx.x, ty = blockIdx.y;   // 2x2 tiles
    const int tid = threadIdx.x;

    __shared__ __align__(16) float sA[76 * 76];
    __shared__ __align__(16) float sB[72 * 72];
    __shared__ float sw[80];
    __shared__ float sb[4];

    if (tid < 75) sw[tid] = w1[(tid / 25) * CC * 25 + c * 25 + (tid % 25)];
    if (tid < 3)  sb[tid] = b1[tid * CC + c];

    const float* xp = x + (size_t)plane * HH * WW;
    const int row0 = ty * 64 - 6, col0 = tx * 64 - 6;

    // avgpool: each item = 2 pooled outputs from 2 float4 loads (aligned)
    for (int i = tid; i < 76 * 38; i += 512) {
        int r = i / 38, j = i % 38;
        int gr = row0 + r;                 // pooled row
        int xc = 2 * col0 + 4 * j;         // x col (16B aligned)
        float4 t0 = make_float4(0.f, 0.f, 0.f, 0.f);
        float4 t1v = make_float4(0.f, 0.f, 0.f, 0.f);
        if ((unsigned)gr < H1 && (unsigned)xc < WW) {
            t0  = *(const float4*)(xp + (size_t)(2 * gr) * WW + xc);
            t1v = *(const float4*)(xp + (size_t)(2 * gr + 1) * WW + xc);
        }
        float p0 = 0.25f * (t0.x + t0.y + t1v.x + t1v.y);
        float p1 = 0.25f * (t0.z + t0.w + t1v.z + t1v.w);
        *(float2*)&sA[r * 76 + 2 * j] = make_float2(p0, p1);
    }
    __syncthreads();

    // conv1: sA(stride 76) -> sB(72x72, stride 72); 36x18 = 648 tiles of 2x4
    {
        float wr[25];
#pragma unroll
        for (int k = 0; k < 25; k++) wr[k] = sw[k];
        const float bv = sb[0];
        for (int t = tid; t < 36 * 18; t += 512) {
            int tr = (t / 18) * 2, tc = (t % 18) * 4;
            float a[2][4];
            conv2x4<76>(&sA[tr * 76 + tc], wr, bv, a);
#pragma unroll
            for (int i = 0; i < 2; i++) {
                int gor = ty * 64 - 4 + tr + i;
                bool rok = (unsigned)gor < H1;
#pragma unroll
                for (int j = 0; j < 4; j++) {
                    int goc = tx * 64 - 4 + tc + j;
                    if (!(rok && (unsigned)goc < W1)) a[i][j] = 0.f;
                }
                *(float4*)&sB[(tr + i) * 72 + tc] =
                    make_float4(a[i][0], a[i][1], a[i][2], a[i][3]);
            }
        }
    }
    __syncthreads();

    // conv2: sB(72) -> sA(68x68, stride 68); 34x17 = 578 tiles
    {
        float wr[25];
#pragma unroll
        for (int k = 0; k < 25; k++) wr[k] = sw[25 + k];
        const float bv = sb[1];
        for (int t = tid; t < 34 * 17; t += 512) {
            int tr = (t / 17) * 2, tc = (t % 17) * 4;
            float a[2][4];
            conv2x4<72>(&sB[tr * 72 + tc], wr, bv, a);
#pragma unroll
            for (int i = 0; i < 2; i++) {
                int gor = ty * 64 - 2 + tr + i;
                bool rok = (unsigned)gor < H1;
#pragma unroll
                for (int j = 0; j < 4; j++) {
                    int goc = tx * 64 - 2 + tc + j;
                    if (!(rok && (unsigned)goc < W1)) a[i][j] = 0.f;
                }
                *(float4*)&sA[(tr + i) * 68 + tc] =
                    make_float4(a[i][0], a[i][1], a[i][2], a[i][3]);
            }
        }
    }
    __syncthreads();

    // conv3: sA(68) -> global 64x64; 32x16 = 512 tiles (exactly one/thread)
    {
        float wr[25];
#pragma unroll
        for (int k = 0; k < 25; k++) wr[k] = sw[50 + k];
        const float bv = sb[2];
        float* tp = t1 + (size_t)plane * H1 * W1;
        const int tr = (tid / 16) * 2, tc = (tid % 16) * 4;
        float a[2][4];
        conv2x4<68>(&sA[tr * 68 + tc], wr, bv, a);
#pragma unroll
        for (int i = 0; i < 2; i++)
            *(float4*)&tp[(size_t)(ty * 64 + tr + i) * W1 + tx * 64 + tc] =
                make_float4(a[i][0], a[i][1], a[i][2], a[i][3]);
    }
}

// ---------------------------------------------------------------------------
// Kernel 2: per-plane maxpool(2x2) + 3x dwconv 5x5 + mean. 68x68 zero-padded
// ping-pong buffers, 512 threads, 2x4 register blocking (512 tiles exact).
// ---------------------------------------------------------------------------
__global__ __launch_bounds__(512, 4) void k_block2(
    const float* __restrict__ t1, const float* __restrict__ w2,
    const float* __restrict__ b2, float* __restrict__ g)
{
    const int plane = blockIdx.x;
    const int c = plane & 63;
    const int tid = threadIdx.x;

    __shared__ __align__(16) float sA[68 * 68];
    __shared__ __align__(16) float sB[68 * 68];
    __shared__ float sw[80];
    __shared__ float sb[4];
    __shared__ float red[8];

    if (tid < 75) sw[tid] = w2[(tid / 25) * CC * 25 + c * 25 + (tid % 25)];
    if (tid < 3)  sb[tid] = b2[tid * CC + c];

    const float* tp = t1 + (size_t)plane * H1 * W1;
    for (int i = tid; i < 68 * 68; i += 512) {
        int r = i / 68, cc2 = i % 68;
        float v = 0.f;
        if (r >= 2 && r < 66 && cc2 >= 2 && cc2 < 66) {
            const float2 a0 = *(const float2*)(tp + (size_t)(2 * (r - 2)) * W1 + 2 * (cc2 - 2));
            const float2 a1 = *(const float2*)(tp + (size_t)(2 * (r - 2) + 1) * W1 + 2 * (cc2 - 2));
            v = fmaxf(fmaxf(a0.x, a0.y), fmaxf(a1.x, a1.y));
        }
        sA[i] = v;
        sB[i] = 0.f;
    }
    __syncthreads();

    const int tr = (tid / 16) * 2, tc = (tid % 16) * 4;   // 2x4 tile, exact
#pragma unroll
    for (int cv = 0; cv < 3; cv++) {
        const float* src = (cv & 1) ? sB : sA;
        float* dst = (cv & 1) ? sA : sB;
        float wr[25];
#pragma unroll
        for (int k = 0; k < 25; k++) wr[k] = sw[cv * 25 + k];
        float a[2][4];
        conv2x4<68>(&src[tr * 68 + tc], wr, sb[cv], a);
#pragma unroll
        for (int i = 0; i < 2; i++) {
            float2* d = (float2*)&dst[(tr + i + 2) * 68 + tc + 2];
            d[0] = make_float2(a[i][0], a[i][1]);
            d[1] = make_float2(a[i][2], a[i][3]);
        }
        __syncthreads();
    }

    // mean of sB interior (cv=2 wrote sB)
    float s = 0.f;
    for (int i = tid; i < 64 * 64; i += 512) {
        int r = i >> 6, cc2 = i & 63;
        s += sB[(r + 2) * 68 + 2 + cc2];
    }
#pragma unroll
    for (int off = 32; off > 0; off >>= 1) s += __shfl_down(s, off);
    if ((tid & 63) == 0) red[tid >> 6] = s;
    __syncthreads();
    if (tid == 0) {
        float t = 0.f;
#pragma unroll
        for (int k = 0; k < 8; k++) t += red[k];
        g[plane] = t * (1.f / 4096.f);
    }
}

// ---------------------------------------------------------------------------
// Kernel 3: kern[o_global] = dot(g[b,:], wk[o,:]) + bk[o];  50*256 = 12800
// ---------------------------------------------------------------------------
__global__ __launch_bounds__(256) void k_kern(
    const float* __restrict__ g, const float* __restrict__ wk,
    const float* __restrict__ bk, float* __restrict__ kern)
{
    const int o = blockIdx.x * 256 + threadIdx.x;     // 0..12799
    const int b = o / 1600, oo = o - b * 1600;
    float v = bk[oo];
    const float* wp = wk + (size_t)oo * 64;
    const float* gp = g + b * 64;
#pragma unroll 16
    for (int k = 0; k < 64; k++) v += gp[k] * wp[k];
    kern[o] = v;
}

// ---------------------------------------------------------------------------
// Kernel 4: dynamic depthwise conv 5x5, 64x64 tile, 4x4 outputs/thread.
// Grid MUST be (4,4,512) for the 64x64 tiling.
// ---------------------------------------------------------------------------
__global__ __launch_bounds__(256) void k_dyn(
    const float* __restrict__ x, const float* __restrict__ kern,
    const float* __restrict__ bias, float* __restrict__ out)
{
    const int plane = blockIdx.z;          // b*64 + c
    const int c = plane & 63;
    const int tx = blockIdx.x, ty = blockIdx.y;   // 4x4 tiles of 64x64
    const int tid = threadIdx.x;

    __shared__ __align__(16) float sx[68 * 68];
    __shared__ float sk[32];
    if (tid < 25) sk[tid] = kern[(size_t)plane * 25 + tid];

    const float* xp = x + (size_t)plane * HH * WW;
    const int row0 = ty * 64 - 2, col0 = tx * 64 - 2;
    for (int i = tid; i < 68 * 68; i += 256) {
        int r = i / 68, cc2 = i % 68;
        int gr = row0 + r, gc = col0 + cc2;
        float v = 0.f;
        if ((unsigned)gr < HH && (unsigned)gc < WW) v = xp[(size_t)gr * WW + gc];
        sx[i] = v;
    }
    __syncthreads();

    float w[25];
#pragma unroll
    for (int k = 0; k < 25; k++) w[k] = sk[k];
    const float bv = bias[c];

    const int tr = (tid >> 4) * 4;      // output row base 0..60
    const int tc = (tid & 15) * 4;      // output col base 0..60
    float acc[4][4];
#pragma unroll
    for (int i = 0; i < 4; i++)
#pragma unroll
        for (int j = 0; j < 4; j++) acc[i][j] = bv;

#pragma unroll
    for (int ir = 0; ir < 8; ir++) {
        const float* s = &sx[(tr + ir) * 68 + tc];
        float4 L = *(const float4*)s;
        float4 R = *(const float4*)(s + 4);
        float e[8] = {L.x, L.y, L.z, L.w, R.x, R.y, R.z, R.w};
#pragma unroll
        for (int i = 0; i < 4; i++) {
            const int ky = ir - i;
            if (ky >= 0 && ky < 5) {
#pragma unroll
                for (int kx = 0; kx < 5; kx++) {
                    const float wv = w[ky * 5 + kx];
#pragma unroll
                    for (int j = 0; j < 4; j++) acc[i][j] += e[j + kx] * wv;
                }
            }
        }
    }

    float* op = out + (size_t)plane * HH * WW + (size_t)(ty * 64 + tr) * WW + tx * 64 + tc;
#pragma unroll
    for (int i = 0; i < 4; i++)
        *(float4*)(op + (size_t)i * WW) = make_float4(acc[i][0], acc[i][1], acc[i][2], acc[i][3]);
}

// ---------------------------------------------------------------------------
extern "C" void kernel_launch(void* const* d_in, const int* in_sizes, int n_in,
                              void* d_out, int out_size, void* d_ws, size_t ws_size,
                              hipStream_t stream)
{
    const float* x    = (const float*)d_in[0];
    const float* w1   = (const float*)d_in[1];
    const float* b1   = (const float*)d_in[2];
    const float* w2   = (const float*)d_in[3];
    const float* b2   = (const float*)d_in[4];
    const float* wk   = (const float*)d_in[5];
    const float* bk   = (const float*)d_in[6];
    const float* bias = (const float*)d_in[7];
    float* out = (float*)d_out;

    float* ws   = (float*)d_ws;
    float* t1   = ws;                       // 512*128*128 floats
    float* g    = ws + 8388608;             // 512 floats
    float* kern = g + 512;                  // 12800 floats

    k_block1<<<dim3(2, 2, 512), 512, 0, stream>>>(x, w1, b1, t1);
    k_block2<<<dim3(512), 512, 0, stream>>>(t1, w2, b2, g);
    k_kern<<<dim3(50), 256, 0, stream>>>(g, wk, bk, kern);
    k_dyn<<<dim3(4, 4, 512), 256, 0, stream>>>(x, kern, bias, out);
}

// Round 5
// 131.107 us; speedup vs baseline: 1.8671x; 1.2333x over previous
//
#include <hip/hip_runtime.h>

#define BB 8
#define CC 64
#define HH 256
#define WW 256
#define H1 128
#define W1 128
#define KK 5

// 4x4 output register block of a 5x5 conv: 8 rows x 2 ds_read_b128, 400 FMA.
// e[m] = src[row][m]; output (i,j) uses e[j+kx], taps w[ky*5+kx], ky=ir-i.
template<int SS>
__device__ __forceinline__ void conv4x4(const float* __restrict__ src,
                                        const float* __restrict__ wr,
                                        float bv, float a[4][4])
{
#pragma unroll
    for (int i = 0; i < 4; i++)
#pragma unroll
        for (int j = 0; j < 4; j++) a[i][j] = bv;
#pragma unroll
    for (int ir = 0; ir < 8; ir++) {
        const float* s = src + ir * SS;
        float4 L = *(const float4*)s;
        float4 R = *(const float4*)(s + 4);
        float e[8] = {L.x, L.y, L.z, L.w, R.x, R.y, R.z, R.w};
#pragma unroll
        for (int i = 0; i < 4; i++) {
            const int ky = ir - i;
            if (ky >= 0 && ky < 5) {
#pragma unroll
                for (int kx = 0; kx < 5; kx++) {
                    const float wv = wr[ky * 5 + kx];
#pragma unroll
                    for (int j = 0; j < 4; j++) a[i][j] += e[j + kx] * wv;
                }
            }
        }
    }
}

// ---------------------------------------------------------------------------
// Kernel 1: fused avgpool(2x2) + 3x depthwise conv 5x5 (block1) on 128x128
// 64x64 tile / block, 512 threads. sA(76x76,s76) -> sB(72x72,s76) -> sA(68x68,s68)
// Weights via uniform (scalar) loads. conv1/conv2 single-pass 4x4 tiles.
// ---------------------------------------------------------------------------
__global__ __launch_bounds__(512, 4) void k_block1(
    const float* __restrict__ x, const float* __restrict__ w1,
    const float* __restrict__ b1, float* __restrict__ t1)
{
    const int plane = blockIdx.z;          // b*64 + c
    const int c = plane & 63;
    const int tx = blockIdx.x, ty = blockIdx.y;   // 2x2 tiles
    const int tid = threadIdx.x;

    __shared__ __align__(16) float sA[76 * 76];
    __shared__ __align__(16) float sB[72 * 76];

    const float* xp = x + (size_t)plane * HH * WW;
    const int row0 = ty * 64 - 6, col0 = tx * 64 - 6;

    // avgpool: each item = 2 pooled outputs from 2 float4 loads (aligned)
    for (int i = tid; i < 76 * 38; i += 512) {
        int r = i / 38, j = i % 38;
        int gr = row0 + r;                 // pooled row
        int xc = 2 * col0 + 4 * j;         // x col (16B aligned)
        float4 t0 = make_float4(0.f, 0.f, 0.f, 0.f);
        float4 t1v = make_float4(0.f, 0.f, 0.f, 0.f);
        if ((unsigned)gr < H1 && (unsigned)xc < WW) {
            t0  = *(const float4*)(xp + (size_t)(2 * gr) * WW + xc);
            t1v = *(const float4*)(xp + (size_t)(2 * gr + 1) * WW + xc);
        }
        float p0 = 0.25f * (t0.x + t0.y + t1v.x + t1v.y);
        float p1 = 0.25f * (t0.z + t0.w + t1v.z + t1v.w);
        *(float2*)&sA[r * 76 + 2 * j] = make_float2(p0, p1);
    }
    __syncthreads();

    // conv1: sA(s76) -> sB(72x72, s76); 18x18 = 324 4x4-tiles, single pass
    {
        float wr[25];
#pragma unroll
        for (int k = 0; k < 25; k++) wr[k] = w1[0 * CC * 25 + c * 25 + k];   // uniform -> SGPR
        const float bv = b1[0 * CC + c];
        if (tid < 324) {
            int tr = (tid / 18) * 4, tc = (tid % 18) * 4;
            float a[4][4];
            conv4x4<76>(&sA[tr * 76 + tc], wr, bv, a);
#pragma unroll
            for (int i = 0; i < 4; i++) {
                int gor = ty * 64 - 4 + tr + i;
                bool rok = (unsigned)gor < H1;
#pragma unroll
                for (int j = 0; j < 4; j++) {
                    int goc = tx * 64 - 4 + tc + j;
                    if (!(rok && (unsigned)goc < W1)) a[i][j] = 0.f;
                }
                *(float4*)&sB[(tr + i) * 76 + tc] =
                    make_float4(a[i][0], a[i][1], a[i][2], a[i][3]);
            }
        }
    }
    __syncthreads();

    // conv2: sB(s76) -> sA(68x68, s68); 17x17 = 289 4x4-tiles, single pass
    {
        float wr[25];
#pragma unroll
        for (int k = 0; k < 25; k++) wr[k] = w1[1 * CC * 25 + c * 25 + k];
        const float bv = b1[1 * CC + c];
        if (tid < 289) {
            int tr = (tid / 17) * 4, tc = (tid % 17) * 4;
            float a[4][4];
            conv4x4<76>(&sB[tr * 76 + tc], wr, bv, a);
#pragma unroll
            for (int i = 0; i < 4; i++) {
                int gor = ty * 64 - 2 + tr + i;
                bool rok = (unsigned)gor < H1;
#pragma unroll
                for (int j = 0; j < 4; j++) {
                    int goc = tx * 64 - 2 + tc + j;
                    if (!(rok && (unsigned)goc < W1)) a[i][j] = 0.f;
                }
                *(float4*)&sA[(tr + i) * 68 + tc] =
                    make_float4(a[i][0], a[i][1], a[i][2], a[i][3]);
            }
        }
    }
    __syncthreads();

    // conv3: sA(s68) -> global 64x64; 32x16 = 512 2x4-tiles (one per thread)
    {
        float wr[25];
#pragma unroll
        for (int k = 0; k < 25; k++) wr[k] = w1[2 * CC * 25 + c * 25 + k];
        const float bv = b1[2 * CC + c];
        float* tp = t1 + (size_t)plane * H1 * W1;
        const int tr = (tid / 16) * 2, tc = (tid % 16) * 4;
        float a[2][4];
#pragma unroll
        for (int i = 0; i < 2; i++)
#pragma unroll
            for (int j = 0; j < 4; j++) a[i][j] = bv;
#pragma unroll
        for (int ir = 0; ir < 6; ir++) {
            const float* s = &sA[(tr + ir) * 68 + tc];
            float4 L = *(const float4*)s;
            float4 R = *(const float4*)(s + 4);
            float e[8] = {L.x, L.y, L.z, L.w, R.x, R.y, R.z, R.w};
#pragma unroll
            for (int i = 0; i < 2; i++) {
                const int ky = ir - i;
                if (ky >= 0 && ky < 5) {
#pragma unroll
                    for (int kx = 0; kx < 5; kx++) {
                        const float wv = wr[ky * 5 + kx];
#pragma unroll
                        for (int j = 0; j < 4; j++) a[i][j] += e[j + kx] * wv;
                    }
                }
            }
        }
#pragma unroll
        for (int i = 0; i < 2; i++)
            *(float4*)&tp[(size_t)(ty * 64 + tr + i) * W1 + tx * 64 + tc] =
                make_float4(a[i][0], a[i][1], a[i][2], a[i][3]);
    }
}

// ---------------------------------------------------------------------------
// Kernel 2: per-plane maxpool(2x2) + 3x dwconv 5x5 + mean. 68x68 zero-padded
// ping-pong buffers, 512 threads, 2x4 register blocking (512 tiles exact).
// ---------------------------------------------------------------------------
__global__ __launch_bounds__(512, 4) void k_block2(
    const float* __restrict__ t1, const float* __restrict__ w2,
    const float* __restrict__ b2, float* __restrict__ g)
{
    const int plane = blockIdx.x;
    const int c = plane & 63;
    const int tid = threadIdx.x;

    __shared__ __align__(16) float sA[68 * 68];
    __shared__ __align__(16) float sB[68 * 68];
    __shared__ float red[8];

    const float* tp = t1 + (size_t)plane * H1 * W1;
    for (int i = tid; i < 68 * 68; i += 512) {
        int r = i / 68, cc2 = i % 68;
        float v = 0.f;
        if (r >= 2 && r < 66 && cc2 >= 2 && cc2 < 66) {
            const float2 a0 = *(const float2*)(tp + (size_t)(2 * (r - 2)) * W1 + 2 * (cc2 - 2));
            const float2 a1 = *(const float2*)(tp + (size_t)(2 * (r - 2) + 1) * W1 + 2 * (cc2 - 2));
            v = fmaxf(fmaxf(a0.x, a0.y), fmaxf(a1.x, a1.y));
        }
        sA[i] = v;
        sB[i] = 0.f;
    }
    __syncthreads();

    const int tr = (tid / 16) * 2, tc = (tid % 16) * 4;   // 2x4 tile, exact
#pragma unroll
    for (int cv = 0; cv < 3; cv++) {
        const float* src = (cv & 1) ? sB : sA;
        float* dst = (cv & 1) ? sA : sB;
        float wr[25];
#pragma unroll
        for (int k = 0; k < 25; k++) wr[k] = w2[cv * CC * 25 + c * 25 + k];  // uniform
        const float bv = b2[cv * CC + c];
        float a[2][4];
#pragma unroll
        for (int i = 0; i < 2; i++)
#pragma unroll
            for (int j = 0; j < 4; j++) a[i][j] = bv;
#pragma unroll
        for (int ir = 0; ir < 6; ir++) {
            const float* s = &src[(tr + ir) * 68 + tc];
            float4 L = *(const float4*)s;
            float4 R = *(const float4*)(s + 4);
            float e[8] = {L.x, L.y, L.z, L.w, R.x, R.y, R.z, R.w};
#pragma unroll
            for (int i = 0; i < 2; i++) {
                const int ky = ir - i;
                if (ky >= 0 && ky < 5) {
#pragma unroll
                    for (int kx = 0; kx < 5; kx++) {
                        const float wv = wr[ky * 5 + kx];
#pragma unroll
                        for (int j = 0; j < 4; j++) a[i][j] += e[j + kx] * wv;
                    }
                }
            }
        }
#pragma unroll
        for (int i = 0; i < 2; i++) {
            float2* d = (float2*)&dst[(tr + i + 2) * 68 + tc + 2];
            d[0] = make_float2(a[i][0], a[i][1]);
            d[1] = make_float2(a[i][2], a[i][3]);
        }
        __syncthreads();
    }

    // mean of sB interior (cv=2 wrote sB)
    float s = 0.f;
    for (int i = tid; i < 64 * 64; i += 512) {
        int r = i >> 6, cc2 = i & 63;
        s += sB[(r + 2) * 68 + 2 + cc2];
    }
#pragma unroll
    for (int off = 32; off > 0; off >>= 1) s += __shfl_down(s, off);
    if ((tid & 63) == 0) red[tid >> 6] = s;
    __syncthreads();
    if (tid == 0) {
        float t = 0.f;
#pragma unroll
        for (int k = 0; k < 8; k++) t += red[k];
        g[plane] = t * (1.f / 4096.f);
    }
}

// ---------------------------------------------------------------------------
// Kernel 3: kern[o_global] = dot(g[b,:], wk[o,:]) + bk[o];  50*256 = 12800
// ---------------------------------------------------------------------------
__global__ __launch_bounds__(256) void k_kern(
    const float* __restrict__ g, const float* __restrict__ wk,
    const float* __restrict__ bk, float* __restrict__ kern)
{
    const int o = blockIdx.x * 256 + threadIdx.x;     // 0..12799
    const int b = o / 1600, oo = o - b * 1600;
    float v = bk[oo];
    const float* wp = wk + (size_t)oo * 64;
    const float* gp = g + b * 64;
#pragma unroll 16
    for (int k = 0; k < 64; k++) v += gp[k] * wp[k];
    kern[o] = v;
}

// ---------------------------------------------------------------------------
// Kernel 4: dynamic depthwise conv 5x5, 64x64 tile, 4x4 outputs/thread.
// Vectorized fill: aligned float4 window [C0-4, C0+68) x rows [R0-2, R0+66),
// LDS stride 76. Kernel weights via uniform scalar loads. Grid (4,4,512).
// ---------------------------------------------------------------------------
__global__ __launch_bounds__(256) void k_dyn(
    const float* __restrict__ x, const float* __restrict__ kern,
    const float* __restrict__ bias, float* __restrict__ out)
{
    const int plane = blockIdx.z;          // b*64 + c
    const int tx = blockIdx.x, ty = blockIdx.y;   // 4x4 tiles of 64x64
    const int tid = threadIdx.x;

    __shared__ __align__(16) float sx[68 * 76];

    const float* xp = x + (size_t)plane * HH * WW;
    const int R0 = ty * 64, C0 = tx * 64;

    // fill: 68 rows x 18 float4 = 1224 items
#pragma unroll
    for (int k = 0; k < 5; k++) {
        int i = tid + k * 256;
        if (i < 68 * 18) {
            int r = i / 18, q = i - r * 18;
            int gr = R0 - 2 + r;
            int gc = C0 - 4 + 4 * q;
            float4 v = make_float4(0.f, 0.f, 0.f, 0.f);
            if ((unsigned)gr < HH && (unsigned)gc < WW)
                v = *(const float4*)(xp + (size_t)gr * WW + gc);
            *(float4*)&sx[r * 76 + 4 * q] = v;
        }
    }

    float w[25];
#pragma unroll
    for (int k = 0; k < 25; k++) w[k] = kern[(size_t)plane * 25 + k];   // uniform -> SGPR
    const float bv = bias[plane & 63];

    __syncthreads();

    const int tr = (tid >> 4) * 4;      // output row base 0..60
    const int tc = (tid & 15) * 4;      // output col base 0..60
    float acc[4][4];
#pragma unroll
    for (int i = 0; i < 4; i++)
#pragma unroll
        for (int j = 0; j < 4; j++) acc[i][j] = bv;

#pragma unroll
    for (int ir = 0; ir < 8; ir++) {
        const float* s = &sx[(tr + ir) * 76 + tc];
        float4 A = *(const float4*)s;
        float4 B4 = *(const float4*)(s + 4);
        float4 Cv = *(const float4*)(s + 8);
        float e[12] = {A.x, A.y, A.z, A.w, B4.x, B4.y, B4.z, B4.w,
                       Cv.x, Cv.y, Cv.z, Cv.w};
#pragma unroll
        for (int i = 0; i < 4; i++) {
            const int ky = ir - i;
            if (ky >= 0 && ky < 5) {
#pragma unroll
                for (int kx = 0; kx < 5; kx++) {
                    const float wv = w[ky * 5 + kx];
#pragma unroll
                    for (int j = 0; j < 4; j++) acc[i][j] += e[j + kx + 2] * wv;
                }
            }
        }
    }

    float* op = out + (size_t)plane * HH * WW + (size_t)(R0 + tr) * WW + C0 + tc;
#pragma unroll
    for (int i = 0; i < 4; i++)
        *(float4*)(op + (size_t)i * WW) = make_float4(acc[i][0], acc[i][1], acc[i][2], acc[i][3]);
}

// ---------------------------------------------------------------------------
extern "C" void kernel_launch(void* const* d_in, const int* in_sizes, int n_in,
                              void* d_out, int out_size, void* d_ws, size_t ws_size,
                              hipStream_t stream)
{
    const float* x    = (const float*)d_in[0];
    const float* w1   = (const float*)d_in[1];
    const float* b1   = (const float*)d_in[2];
    const float* w2   = (const float*)d_in[3];
    const float* b2   = (const float*)d_in[4];
    const float* wk   = (const float*)d_in[5];
    const float* bk   = (const float*)d_in[6];
    const float* bias = (const float*)d_in[7];
    float* out = (float*)d_out;

    float* ws   = (float*)d_ws;
    float* t1   = ws;                       // 512*128*128 floats
    float* g    = ws + 8388608;             // 512 floats
    float* kern = g + 512;                  // 12800 floats

    k_block1<<<dim3(2, 2, 512), 512, 0, stream>>>(x, w1, b1, t1);
    k_block2<<<dim3(512), 512, 0, stream>>>(t1, w2, b2, g);
    k_kern<<<dim3(50), 256, 0, stream>>>(g, wk, bk, kern);
    k_dyn<<<dim3(4, 4, 512), 256, 0, stream>>>(x, kern, bias, out);
}

// Round 6
// 121.406 us; speedup vs baseline: 2.0163x; 1.0799x over previous
//
#include <hip/hip_runtime.h>

#define BB 8
#define CC 64
#define HH 256
#define WW 256
#define H1 128
#define W1 128
#define KK 5

// 4x4 output register block of a 5x5 conv: 8 rows x 2 ds_read_b128, 400 FMA.
template<int SS>
__device__ __forceinline__ void conv4x4(const float* __restrict__ src,
                                        const float* __restrict__ wr,
                                        float bv, float a[4][4])
{
#pragma unroll
    for (int i = 0; i < 4; i++)
#pragma unroll
        for (int j = 0; j < 4; j++) a[i][j] = bv;
#pragma unroll
    for (int ir = 0; ir < 8; ir++) {
        const float* s = src + ir * SS;
        float4 L = *(const float4*)s;
        float4 R = *(const float4*)(s + 4);
        float e[8] = {L.x, L.y, L.z, L.w, R.x, R.y, R.z, R.w};
#pragma unroll
        for (int i = 0; i < 4; i++) {
            const int ky = ir - i;
            if (ky >= 0 && ky < 5) {
#pragma unroll
                for (int kx = 0; kx < 5; kx++) {
                    const float wv = wr[ky * 5 + kx];
#pragma unroll
                    for (int j = 0; j < 4; j++) a[i][j] += e[j + kx] * wv;
                }
            }
        }
    }
}

// 1x4 output strip of a 5x5 conv: 5 rows x 2 ds_read_b128, 100 FMA.
template<int SS>
__device__ __forceinline__ void conv1x4(const float* __restrict__ src,
                                        const float* __restrict__ wr,
                                        float bv, float a[4])
{
#pragma unroll
    for (int j = 0; j < 4; j++) a[j] = bv;
#pragma unroll
    for (int ir = 0; ir < 5; ir++) {
        const float* s = src + ir * SS;
        float4 L = *(const float4*)s;
        float4 R = *(const float4*)(s + 4);
        float e[8] = {L.x, L.y, L.z, L.w, R.x, R.y, R.z, R.w};
#pragma unroll
        for (int kx = 0; kx < 5; kx++) {
            const float wv = wr[ir * 5 + kx];
#pragma unroll
            for (int j = 0; j < 4; j++) a[j] += e[j + kx] * wv;
        }
    }
}

// ---------------------------------------------------------------------------
// Fused kernel: avgpool + 3x dwconv(128^2) + maxpool + 3x dwconv(64^2) + mean
// One 1024-thread block per (b,c) plane. Full plane in LDS, zero-padded
// 132x132 ping-pong buffers (139 KB). Third 64^2 conv feeds the mean directly
// (never stored). Weights/bias via block-uniform scalar loads.
// ---------------------------------------------------------------------------
__global__ __launch_bounds__(1024, 4) void k_block12(
    const float* __restrict__ x, const float* __restrict__ w1,
    const float* __restrict__ b1, const float* __restrict__ w2,
    const float* __restrict__ b2, float* __restrict__ g)
{
    const int plane = blockIdx.x;          // b*64 + c
    const int c = plane & 63;
    const int tid = threadIdx.x;

    __shared__ __align__(16) float sA[132 * 132];
    __shared__ __align__(16) float sB[132 * 132];
    __shared__ float red[16];

    const float* xp = x + (size_t)plane * HH * WW;

    // zero sB (its border ring must be 0; interior overwritten by conv1)
#pragma unroll
    for (int k = 0; k < 5; k++) {
        int i = tid + k * 1024;
        if (i < 132 * 132 / 4)
            ((float4*)sB)[i] = make_float4(0.f, 0.f, 0.f, 0.f);
    }

    // fill sA: avgpool(2x2) of x into interior [2,130)^2, zero borders.
    // item = one float2 (two pooled cols); 66 pairs per row.
#pragma unroll
    for (int k = 0; k < 9; k++) {
        int i = tid + k * 1024;
        if (i < 132 * 66) {
            int r = i / 66, c2 = i % 66;
            float2 v = make_float2(0.f, 0.f);
            if (r >= 2 && r < 130 && c2 >= 1 && c2 <= 64) {
                int pr = r - 2;            // pooled row 0..127
                int xc = 4 * c2 - 4;       // x col, 16B aligned
                float4 a0 = *(const float4*)(xp + (size_t)(2 * pr) * WW + xc);
                float4 a1 = *(const float4*)(xp + (size_t)(2 * pr + 1) * WW + xc);
                v.x = 0.25f * (a0.x + a0.y + a1.x + a1.y);
                v.y = 0.25f * (a0.z + a0.w + a1.z + a1.w);
            }
            *(float2*)&sA[r * 132 + 2 * c2] = v;
        }
    }
    __syncthreads();

    // Stage A: 3 convs at 128^2; 32x32 grid of 4x4 tiles (1024 threads exact)
    // ping-pong: sA -> sB -> sA -> sB
    {
        const int tr = (tid >> 5) * 4, tc = (tid & 31) * 4;
#pragma unroll
        for (int cv = 0; cv < 3; cv++) {
            const float* src = (cv & 1) ? sB : sA;
            float* dst = (cv & 1) ? sA : sB;
            float wr[25];
#pragma unroll
            for (int k = 0; k < 25; k++) wr[k] = w1[cv * CC * 25 + c * 25 + k];
            const float bv = b1[cv * CC + c];
            float a[4][4];
            conv4x4<132>(&src[tr * 132 + tc], wr, bv, a);
#pragma unroll
            for (int i = 0; i < 4; i++) {
                float2* d = (float2*)&dst[(tr + i + 2) * 132 + tc + 2];
                d[0] = make_float2(a[i][0], a[i][1]);
                d[1] = make_float2(a[i][2], a[i][3]);
            }
            __syncthreads();
        }
    }

    // maxpool: sB interior (128^2) -> pB (68x76 zero-padded); also zero pC.
    float* pB = sA;              // 68*76 = 5168 floats
    float* pC = sA + 5440;       // disjoint region of sA
    for (int i = tid; i < 68 * 76; i += 1024) {
        int r = i / 76, cc2 = i % 76;
        float v = 0.f;
        if (r >= 2 && r < 66 && cc2 >= 2 && cc2 < 66) {
            const float* p = &sB[(size_t)(2 * (r - 2) + 2) * 132 + 2 * (cc2 - 2) + 2];
            v = fmaxf(fmaxf(p[0], p[1]), fmaxf(p[132], p[133]));
        }
        pB[i] = v;
        pC[i] = 0.f;
    }
    __syncthreads();

    // Stage B: convs at 64^2; 64 rows x 16 strips of 1x4 (1024 threads exact)
    const int r = tid >> 4, c0 = (tid & 15) * 4;
    {
        float wr[25];
#pragma unroll
        for (int k = 0; k < 25; k++) wr[k] = w2[0 * CC * 25 + c * 25 + k];
        float a[4];
        conv1x4<76>(&pB[r * 76 + c0], wr, b2[0 * CC + c], a);
        float2* d = (float2*)&pC[(r + 2) * 76 + c0 + 2];
        d[0] = make_float2(a[0], a[1]);
        d[1] = make_float2(a[2], a[3]);
    }
    __syncthreads();
    {
        float wr[25];
#pragma unroll
        for (int k = 0; k < 25; k++) wr[k] = w2[1 * CC * 25 + c * 25 + k];
        float a[4];
        conv1x4<76>(&pC[r * 76 + c0], wr, b2[1 * CC + c], a);
        float2* d = (float2*)&pB[(r + 2) * 76 + c0 + 2];
        d[0] = make_float2(a[0], a[1]);
        d[1] = make_float2(a[2], a[3]);
    }
    __syncthreads();
    // conv3 feeds the mean directly -- no store
    float s;
    {
        float wr[25];
#pragma unroll
        for (int k = 0; k < 25; k++) wr[k] = w2[2 * CC * 25 + c * 25 + k];
        float a[4];
        conv1x4<76>(&pB[r * 76 + c0], wr, b2[2 * CC + c], a);
        s = a[0] + a[1] + a[2] + a[3];
    }
#pragma unroll
    for (int off = 32; off > 0; off >>= 1) s += __shfl_down(s, off);
    if ((tid & 63) == 0) red[tid >> 6] = s;
    __syncthreads();
    if (tid == 0) {
        float t = 0.f;
#pragma unroll
        for (int k = 0; k < 16; k++) t += red[k];
        g[plane] = t * (1.f / 4096.f);
    }
}

// ---------------------------------------------------------------------------
// Kernel 3: kern[o_global] = dot(g[b,:], wk[o,:]) + bk[o];  50*256 = 12800
// ---------------------------------------------------------------------------
__global__ __launch_bounds__(256) void k_kern(
    const float* __restrict__ g, const float* __restrict__ wk,
    const float* __restrict__ bk, float* __restrict__ kern)
{
    const int o = blockIdx.x * 256 + threadIdx.x;     // 0..12799
    const int b = o / 1600, oo = o - b * 1600;
    float v = bk[oo];
    const float* wp = wk + (size_t)oo * 64;
    const float* gp = g + b * 64;
#pragma unroll 16
    for (int k = 0; k < 64; k++) v += gp[k] * wp[k];
    kern[o] = v;
}

// ---------------------------------------------------------------------------
// Kernel 4: dynamic depthwise conv 5x5, 64x64 tile, 4x4 outputs/thread.
// Vectorized fill: aligned float4 window [C0-4, C0+68) x rows [R0-2, R0+66),
// LDS stride 76. Kernel weights via uniform scalar loads. Grid (4,4,512).
// ---------------------------------------------------------------------------
__global__ __launch_bounds__(256) void k_dyn(
    const float* __restrict__ x, const float* __restrict__ kern,
    const float* __restrict__ bias, float* __restrict__ out)
{
    const int plane = blockIdx.z;          // b*64 + c
    const int tx = blockIdx.x, ty = blockIdx.y;   // 4x4 tiles of 64x64
    const int tid = threadIdx.x;

    __shared__ __align__(16) float sx[68 * 76];

    const float* xp = x + (size_t)plane * HH * WW;
    const int R0 = ty * 64, C0 = tx * 64;

    // fill: 68 rows x 18 float4 = 1224 items
#pragma unroll
    for (int k = 0; k < 5; k++) {
        int i = tid + k * 256;
        if (i < 68 * 18) {
            int r = i / 18, q = i - r * 18;
            int gr = R0 - 2 + r;
            int gc = C0 - 4 + 4 * q;
            float4 v = make_float4(0.f, 0.f, 0.f, 0.f);
            if ((unsigned)gr < HH && (unsigned)gc < WW)
                v = *(const float4*)(xp + (size_t)gr * WW + gc);
            *(float4*)&sx[r * 76 + 4 * q] = v;
        }
    }

    float w[25];
#pragma unroll
    for (int k = 0; k < 25; k++) w[k] = kern[(size_t)plane * 25 + k];   // uniform -> SGPR
    const float bv = bias[plane & 63];

    __syncthreads();

    const int tr = (tid >> 4) * 4;      // output row base 0..60
    const int tc = (tid & 15) * 4;      // output col base 0..60
    float acc[4][4];
#pragma unroll
    for (int i = 0; i < 4; i++)
#pragma unroll
        for (int j = 0; j < 4; j++) acc[i][j] = bv;

#pragma unroll
    for (int ir = 0; ir < 8; ir++) {
        const float* s = &sx[(tr + ir) * 76 + tc];
        float4 A = *(const float4*)s;
        float4 B4 = *(const float4*)(s + 4);
        float4 Cv = *(const float4*)(s + 8);
        float e[12] = {A.x, A.y, A.z, A.w, B4.x, B4.y, B4.z, B4.w,
                       Cv.x, Cv.y, Cv.z, Cv.w};
#pragma unroll
        for (int i = 0; i < 4; i++) {
            const int ky = ir - i;
            if (ky >= 0 && ky < 5) {
#pragma unroll
                for (int kx = 0; kx < 5; kx++) {
                    const float wv = w[ky * 5 + kx];
#pragma unroll
                    for (int j = 0; j < 4; j++) acc[i][j] += e[j + kx + 2] * wv;
                }
            }
        }
    }

    float* op = out + (size_t)plane * HH * WW + (size_t)(R0 + tr) * WW + C0 + tc;
#pragma unroll
    for (int i = 0; i < 4; i++)
        *(float4*)(op + (size_t)i * WW) = make_float4(acc[i][0], acc[i][1], acc[i][2], acc[i][3]);
}

// ---------------------------------------------------------------------------
extern "C" void kernel_launch(void* const* d_in, const int* in_sizes, int n_in,
                              void* d_out, int out_size, void* d_ws, size_t ws_size,
                              hipStream_t stream)
{
    const float* x    = (const float*)d_in[0];
    const float* w1   = (const float*)d_in[1];
    const float* b1   = (const float*)d_in[2];
    const float* w2   = (const float*)d_in[3];
    const float* b2   = (const float*)d_in[4];
    const float* wk   = (const float*)d_in[5];
    const float* bk   = (const float*)d_in[6];
    const float* bias = (const float*)d_in[7];
    float* out = (float*)d_out;

    float* ws   = (float*)d_ws;
    float* g    = ws;                       // 512 floats
    float* kern = ws + 512;                 // 12800 floats

    k_block12<<<dim3(512), 1024, 0, stream>>>(x, w1, b1, w2, b2, g);
    k_kern<<<dim3(50), 256, 0, stream>>>(g, wk, bk, kern);
    k_dyn<<<dim3(4, 4, 512), 256, 0, stream>>>(x, kern, bias, out);
}

// Round 7
// 116.425 us; speedup vs baseline: 2.1026x; 1.0428x over previous
//
#include <hip/hip_runtime.h>

#define BB 8
#define CC 64
#define HH 256
#define WW 256
#define H1 128
#define W1 128
#define KK 5

// 4x4 output register block of a 5x5 conv: 8 rows x 2 ds_read_b128, 400 FMA.
template<int SS>
__device__ __forceinline__ void conv4x4(const float* __restrict__ src,
                                        const float* __restrict__ wr,
                                        float bv, float a[4][4])
{
#pragma unroll
    for (int i = 0; i < 4; i++)
#pragma unroll
        for (int j = 0; j < 4; j++) a[i][j] = bv;
#pragma unroll
    for (int ir = 0; ir < 8; ir++) {
        const float* s = src + ir * SS;
        float4 L = *(const float4*)s;
        float4 R = *(const float4*)(s + 4);
        float e[8] = {L.x, L.y, L.z, L.w, R.x, R.y, R.z, R.w};
#pragma unroll
        for (int i = 0; i < 4; i++) {
            const int ky = ir - i;
            if (ky >= 0 && ky < 5) {
#pragma unroll
                for (int kx = 0; kx < 5; kx++) {
                    const float wv = wr[ky * 5 + kx];
#pragma unroll
                    for (int j = 0; j < 4; j++) a[i][j] += e[j + kx] * wv;
                }
            }
        }
    }
}

// 1x4 output strip of a 5x5 conv: 5 rows x 2 ds_read_b128, 100 FMA.
template<int SS>
__device__ __forceinline__ void conv1x4(const float* __restrict__ src,
                                        const float* __restrict__ wr,
                                        float bv, float a[4])
{
#pragma unroll
    for (int j = 0; j < 4; j++) a[j] = bv;
#pragma unroll
    for (int ir = 0; ir < 5; ir++) {
        const float* s = src + ir * SS;
        float4 L = *(const float4*)s;
        float4 R = *(const float4*)(s + 4);
        float e[8] = {L.x, L.y, L.z, L.w, R.x, R.y, R.z, R.w};
#pragma unroll
        for (int kx = 0; kx < 5; kx++) {
            const float wv = wr[ir * 5 + kx];
#pragma unroll
            for (int j = 0; j < 4; j++) a[j] += e[j + kx] * wv;
        }
    }
}

// ---------------------------------------------------------------------------
// Fused reduction chain, ONE 132x132 LDS buffer (69.7 KB -> 2 blocks/CU):
// avgpool + 3x dwconv(128^2, IN-PLACE via reg+barrier) + maxpool(->front of
// same buffer) + 3x dwconv(64^2) + mean. 1024 threads, one block per plane.
// __launch_bounds__(1024,8) pins VGPR<=64 so two blocks co-reside per CU.
// ---------------------------------------------------------------------------
__global__ __launch_bounds__(1024, 8) void k_a(
    const float* __restrict__ x, const float* __restrict__ w1,
    const float* __restrict__ b1, const float* __restrict__ w2,
    const float* __restrict__ b2, float* __restrict__ g)
{
    const int plane = blockIdx.x;          // b*64 + c
    const int c = plane & 63;
    const int tid = threadIdx.x;

    __shared__ __align__(16) float sA[132 * 132];
    __shared__ float red[16];

    const float* xp = x + (size_t)plane * HH * WW;

    // fill sA: avgpool(2x2) of x into interior [2,130)^2, zero borders.
    // item = one float2 (two pooled cols); 66 pairs per row; border stays 0
    // for the whole of Stage A (convs write interior only).
#pragma unroll
    for (int k = 0; k < 9; k++) {
        int i = tid + k * 1024;
        if (i < 132 * 66) {
            int r = i / 66, c2 = i % 66;
            float2 v = make_float2(0.f, 0.f);
            if (r >= 2 && r < 130 && c2 >= 1 && c2 <= 64) {
                int pr = r - 2;            // pooled row 0..127
                int xc = 4 * c2 - 4;       // x col, 16B aligned
                float4 a0 = *(const float4*)(xp + (size_t)(2 * pr) * WW + xc);
                float4 a1 = *(const float4*)(xp + (size_t)(2 * pr + 1) * WW + xc);
                v.x = 0.25f * (a0.x + a0.y + a1.x + a1.y);
                v.y = 0.25f * (a0.z + a0.w + a1.z + a1.w);
            }
            *(float2*)&sA[r * 132 + 2 * c2] = v;
        }
    }
    __syncthreads();

    // Stage A: 3 convs at 128^2, IN PLACE. 32x32 grid of 4x4 tiles (exact).
    // All threads read into registers, barrier, all write back, barrier.
    {
        const int tr = (tid >> 5) * 4, tc = (tid & 31) * 4;
#pragma unroll
        for (int cv = 0; cv < 3; cv++) {
            float wr[25];
#pragma unroll
            for (int k = 0; k < 25; k++) wr[k] = w1[cv * CC * 25 + c * 25 + k];
            const float bv = b1[cv * CC + c];
            float a[4][4];
            conv4x4<132>(&sA[tr * 132 + tc], wr, bv, a);
            __syncthreads();
#pragma unroll
            for (int i = 0; i < 4; i++) {
                float2* d = (float2*)&sA[(tr + i + 2) * 132 + tc + 2];
                d[0] = make_float2(a[i][0], a[i][1]);
                d[1] = make_float2(a[i][2], a[i][3]);
            }
            __syncthreads();
        }
    }

    // maxpool 128^2 -> 64^2, through registers, into the FRONT of sA.
    // pB = sA[0 .. 5168), pC = sA[5440 .. 10608): both 68x76 zero-padded.
    float* pB = sA;
    float* pC = sA + 5440;
    float m[4];
    const int mr = (tid * 4) >> 6;          // pooled row 0..63 (same for k=0..3)
    const int mc0 = (tid * 4) & 63;         // pooled col base
#pragma unroll
    for (int k = 0; k < 4; k++) {
        const float* p = &sA[(size_t)(2 * mr + 2) * 132 + 2 * (mc0 + k) + 2];
        m[k] = fmaxf(fmaxf(p[0], p[1]), fmaxf(p[132], p[133]));
    }
    __syncthreads();
#pragma unroll
    for (int k = 0; k < 4; k++)
        pB[(mr + 2) * 76 + mc0 + k + 2] = m[k];
    // zero pB border (1072 slots) + all of pC (5168 slots)
    for (int i = tid; i < 1072 + 5168; i += 1024) {
        if (i < 1072) {
            int idx;
            if (i < 304) {                    // rows 0,1,66,67 full width
                int rr = i / 76;
                int rowz = (rr < 2) ? rr : 64 + rr;
                idx = rowz * 76 + (i % 76);
            } else {                          // rows 2..65, cols 0,1,66..75
                int j = i - 304;
                int row = 2 + j / 12, k2 = j % 12;
                int col = (k2 < 2) ? k2 : 64 + k2;
                idx = row * 76 + col;
            }
            pB[idx] = 0.f;
        } else {
            pC[i - 1072] = 0.f;
        }
    }
    __syncthreads();

    // Stage B: convs at 64^2; 64 rows x 16 strips of 1x4 (1024 threads exact)
    const int r = tid >> 4, c0 = (tid & 15) * 4;
    {
        float wr[25];
#pragma unroll
        for (int k = 0; k < 25; k++) wr[k] = w2[0 * CC * 25 + c * 25 + k];
        float a[4];
        conv1x4<76>(&pB[r * 76 + c0], wr, b2[0 * CC + c], a);
        float2* d = (float2*)&pC[(r + 2) * 76 + c0 + 2];
        d[0] = make_float2(a[0], a[1]);
        d[1] = make_float2(a[2], a[3]);
    }
    __syncthreads();
    {
        float wr[25];
#pragma unroll
        for (int k = 0; k < 25; k++) wr[k] = w2[1 * CC * 25 + c * 25 + k];
        float a[4];
        conv1x4<76>(&pC[r * 76 + c0], wr, b2[1 * CC + c], a);
        float2* d = (float2*)&pB[(r + 2) * 76 + c0 + 2];
        d[0] = make_float2(a[0], a[1]);
        d[1] = make_float2(a[2], a[3]);
    }
    __syncthreads();
    // conv3 feeds the mean directly -- no store
    float s;
    {
        float wr[25];
#pragma unroll
        for (int k = 0; k < 25; k++) wr[k] = w2[2 * CC * 25 + c * 25 + k];
        float a[4];
        conv1x4<76>(&pB[r * 76 + c0], wr, b2[2 * CC + c], a);
        s = a[0] + a[1] + a[2] + a[3];
    }
#pragma unroll
    for (int off = 32; off > 0; off >>= 1) s += __shfl_down(s, off);
    if ((tid & 63) == 0) red[tid >> 6] = s;
    __syncthreads();
    if (tid == 0) {
        float t = 0.f;
#pragma unroll
        for (int k = 0; k < 16; k++) t += red[k];
        g[plane] = t * (1.f / 4096.f);
    }
}

// ---------------------------------------------------------------------------
// Kernel 3: kern[o_global] = dot(g[b,:], wk[o,:]) + bk[o];  50*256 = 12800
// ---------------------------------------------------------------------------
__global__ __launch_bounds__(256) void k_kern(
    const float* __restrict__ g, const float* __restrict__ wk,
    const float* __restrict__ bk, float* __restrict__ kern)
{
    const int o = blockIdx.x * 256 + threadIdx.x;     // 0..12799
    const int b = o / 1600, oo = o - b * 1600;
    float v = bk[oo];
    const float* wp = wk + (size_t)oo * 64;
    const float* gp = g + b * 64;
#pragma unroll 16
    for (int k = 0; k < 64; k++) v += gp[k] * wp[k];
    kern[o] = v;
}

// ---------------------------------------------------------------------------
// Kernel 4: dynamic depthwise conv 5x5, 64x64 tile, 4x4 outputs/thread.
// Vectorized fill: aligned float4 window [C0-4, C0+68) x rows [R0-2, R0+66),
// LDS stride 76. Kernel weights via uniform scalar loads. Grid (4,4,512).
// ---------------------------------------------------------------------------
__global__ __launch_bounds__(256) void k_dyn(
    const float* __restrict__ x, const float* __restrict__ kern,
    const float* __restrict__ bias, float* __restrict__ out)
{
    const int plane = blockIdx.z;          // b*64 + c
    const int tx = blockIdx.x, ty = blockIdx.y;   // 4x4 tiles of 64x64
    const int tid = threadIdx.x;

    __shared__ __align__(16) float sx[68 * 76];

    const float* xp = x + (size_t)plane * HH * WW;
    const int R0 = ty * 64, C0 = tx * 64;

    // fill: 68 rows x 18 float4 = 1224 items
#pragma unroll
    for (int k = 0; k < 5; k++) {
        int i = tid + k * 256;
        if (i < 68 * 18) {
            int r = i / 18, q = i - r * 18;
            int gr = R0 - 2 + r;
            int gc = C0 - 4 + 4 * q;
            float4 v = make_float4(0.f, 0.f, 0.f, 0.f);
            if ((unsigned)gr < HH && (unsigned)gc < WW)
                v = *(const float4*)(xp + (size_t)gr * WW + gc);
            *(float4*)&sx[r * 76 + 4 * q] = v;
        }
    }

    float w[25];
#pragma unroll
    for (int k = 0; k < 25; k++) w[k] = kern[(size_t)plane * 25 + k];   // uniform -> SGPR
    const float bv = bias[plane & 63];

    __syncthreads();

    const int tr = (tid >> 4) * 4;      // output row base 0..60
    const int tc = (tid & 15) * 4;      // output col base 0..60
    float acc[4][4];
#pragma unroll
    for (int i = 0; i < 4; i++)
#pragma unroll
        for (int j = 0; j < 4; j++) acc[i][j] = bv;

#pragma unroll
    for (int ir = 0; ir < 8; ir++) {
        const float* s = &sx[(tr + ir) * 76 + tc];
        float4 A = *(const float4*)s;
        float4 B4 = *(const float4*)(s + 4);
        float4 Cv = *(const float4*)(s + 8);
        float e[12] = {A.x, A.y, A.z, A.w, B4.x, B4.y, B4.z, B4.w,
                       Cv.x, Cv.y, Cv.z, Cv.w};
#pragma unroll
        for (int i = 0; i < 4; i++) {
            const int ky = ir - i;
            if (ky >= 0 && ky < 5) {
#pragma unroll
                for (int kx = 0; kx < 5; kx++) {
                    const float wv = w[ky * 5 + kx];
#pragma unroll
                    for (int j = 0; j < 4; j++) acc[i][j] += e[j + kx + 2] * wv;
                }
            }
        }
    }

    float* op = out + (size_t)plane * HH * WW + (size_t)(R0 + tr) * WW + C0 + tc;
#pragma unroll
    for (int i = 0; i < 4; i++)
        *(float4*)(op + (size_t)i * WW) = make_float4(acc[i][0], acc[i][1], acc[i][2], acc[i][3]);
}

// ---------------------------------------------------------------------------
extern "C" void kernel_launch(void* const* d_in, const int* in_sizes, int n_in,
                              void* d_out, int out_size, void* d_ws, size_t ws_size,
                              hipStream_t stream)
{
    const float* x    = (const float*)d_in[0];
    const float* w1   = (const float*)d_in[1];
    const float* b1   = (const float*)d_in[2];
    const float* w2   = (const float*)d_in[3];
    const float* b2   = (const float*)d_in[4];
    const float* wk   = (const float*)d_in[5];
    const float* bk   = (const float*)d_in[6];
    const float* bias = (const float*)d_in[7];
    float* out = (float*)d_out;

    float* ws   = (float*)d_ws;
    float* g    = ws;                       // 512 floats
    float* kern = ws + 512;                 // 12800 floats

    k_a<<<dim3(512), 1024, 0, stream>>>(x, w1, b1, w2, b2, g);
    k_kern<<<dim3(50), 256, 0, stream>>>(g, wk, bk, kern);
    k_dyn<<<dim3(4, 4, 512), 256, 0, stream>>>(x, kern, bias, out);
}